// Round 20
// baseline (445.150 us; speedup 1.0000x reference)
//
#include <hip/hip_runtime.h>
#include <hip/hip_bf16.h>
#include <math.h>

// Problem constants
#define B_   16
#define IC_  32
#define HW_  128
#define NF_  8
#define OC_  64
#define K_   5
#define GRP_ 8
#define COTOT_ (OC_ * GRP_)   // 512
#define XTH  132              // padded spatial (128 + 2*2)
#define TAPSTRIDE (COTOT_ * IC_)   // elements per tap in wt
#define XROWB (XTH * IC_ * 2)      // 8448 bytes per xs row
#define HW2  (HW_ * HW_)

typedef short  short8  __attribute__((ext_vector_type(8)));
typedef unsigned short ushort8 __attribute__((ext_vector_type(8)));
typedef float  f32x4   __attribute__((ext_vector_type(4)));

static __device__ inline unsigned short f2bf(float f) {
    unsigned u = __builtin_bit_cast(unsigned, f);
    unsigned r = (u + 0x7FFFu + ((u >> 16) & 1u)) >> 16;
    return (unsigned short)r;
}

// async global -> LDS, 16 bytes per lane (dest = uniform base + lane*16)
__device__ __forceinline__ void gload16(void* lds, const void* g) {
    __builtin_amdgcn_global_load_lds(
        (const __attribute__((address_space(1))) unsigned int*)g,
        (__attribute__((address_space(3))) unsigned int*)lds, 16, 0, 0);
}

// ---------------------------------------------------------------------------
// Kernel 1: x NCHW fp32 -> padded NHWC bf16   xt[b][hp][wp][ic]
// ---------------------------------------------------------------------------
__global__ __launch_bounds__(256) void xform_kernel(
    const float* __restrict__ x, unsigned short* __restrict__ xt) {
    int idx = blockIdx.x * blockDim.x + threadIdx.x;
    const int TOT = B_ * XTH * XTH;
    if (idx >= TOT) return;
    int wp = idx % XTH;
    int t  = idx / XTH;
    int hp = t % XTH;
    int b  = t / XTH;

    unsigned short vals[IC_];
    bool interior = (hp >= 2) && (hp < 2 + HW_) && (wp >= 2) && (wp < 2 + HW_);
    if (interior) {
        const float* xb = x + ((size_t)b * IC_) * HW2 + (hp - 2) * HW_ + (wp - 2);
        #pragma unroll
        for (int ic = 0; ic < IC_; ++ic)
            vals[ic] = f2bf(xb[(size_t)ic * HW2]);
    } else {
        #pragma unroll
        for (int ic = 0; ic < IC_; ++ic) vals[ic] = 0;
    }
    ushort8* dst = (ushort8*)(xt + (size_t)idx * IC_);
    #pragma unroll
    for (int c = 0; c < 4; ++c) {
        ushort8 v;
        #pragma unroll
        for (int j = 0; j < 8; ++j) v[j] = vals[c * 8 + j];
        dst[c] = v;
    }
}

// ---------------------------------------------------------------------------
// Kernel 2: rotated+mixed weights -> bf16, layout wt[tap25][co512][ic32]
// ---------------------------------------------------------------------------
__global__ __launch_bounds__(256) void build_w_kernel(
    const float* __restrict__ kern,
    const float* __restrict__ relaxed,
    unsigned short* __restrict__ wt) {
    int idx = blockIdx.x * blockDim.x + threadIdx.x;
    const int TOT = 25 * COTOT_ * IC_;
    if (idx >= TOT) return;
    int ic = idx & (IC_ - 1);
    int t  = idx >> 5;
    int co = t & (COTOT_ - 1);
    int e  = t >> 9;            // ky*5+kx
    int a  = co & (GRP_ - 1);
    int o  = co >> 3;
    int i  = e / K_;            // ky
    int j  = e - i * K_;        // kx

    float theta = -6.283185307179586f / (float)GRP_ * (float)a;
    float cth = cosf(theta), sth = sinf(theta);
    float bx = (2.0f * (float)j + 1.0f) / (float)K_ - 1.0f;
    float by = (2.0f * (float)i + 1.0f) / (float)K_ - 1.0f;
    float gx = cth * bx - sth * by;
    float gy = sth * bx + cth * by;
    float ix = ((gx + 1.0f) * (float)K_ - 1.0f) * 0.5f;
    float iy = ((gy + 1.0f) * (float)K_ - 1.0f) * 0.5f;
    float x0 = floorf(ix), y0 = floorf(iy);
    float wx1 = ix - x0, wy1 = iy - y0;
    float wx0 = 1.0f - wx1, wy0 = 1.0f - wy1;

    float xs2[2]  = {x0, x0 + 1.0f};
    float ys2[2]  = {y0, y0 + 1.0f};
    float wxs[2] = {wx0, wx1};
    float wys[2] = {wy0, wy1};

    float tw[4];
    int   tyc[4], txc[4];
    #pragma unroll
    for (int dy = 0; dy < 2; ++dy) {
        #pragma unroll
        for (int dx = 0; dx < 2; ++dx) {
            float xx = xs2[dx], yy = ys2[dy];
            bool valid = (xx >= 0.0f) && (xx < (float)K_) &&
                         (yy >= 0.0f) && (yy < (float)K_);
            int tp = dy * 2 + dx;
            tw[tp]  = wys[dy] * wxs[dx] * (valid ? 1.0f : 0.0f);
            txc[tp] = (int)fminf(fmaxf(xx, 0.0f), (float)(K_ - 1));
            tyc[tp] = (int)fminf(fmaxf(yy, 0.0f), (float)(K_ - 1));
        }
    }

    float acc = 0.0f;
    #pragma unroll
    for (int n = 0; n < NF_; ++n) {
        const float* kb = kern + ((size_t)((n * OC_ + o) * IC_ + ic)) * (K_ * K_);
        float v = 0.0f;
        #pragma unroll
        for (int tp = 0; tp < 4; ++tp)
            v += kb[tyc[tp] * K_ + txc[tp]] * tw[tp];
        acc += relaxed[n * GRP_ + a] * v;
    }
    wt[idx] = f2bf(acc);
}

// ---------------------------------------------------------------------------
// Kernel 3: MFMA implicit-GEMM conv + leaky relu
// (R18 structure + 2-cg PERSISTENT BLOCK)
// wave  = 64 co x 128 w x 1 h (4x8 frags 16x16); block = 4 waves
// Each block stages its x slab ONCE and computes TWO cg groups (a pair):
//   - cg1's tap-0 A prefetch issues BEFORE cg0's stores (in-order vmcnt
//     retire: af loads retire first) -> cg0's store drain hides under
//     cg1's full 25-tap compute, deterministically within the wave.
//   - slab staging + prologue amortized 2x (xt fetch traffic halves).
// Grid 2048 (%8==0), T1 bijective XCD remap: each XCD owns one cg-pair
// slice (~205 KB, L2-resident) with hp-contiguous dispatch.
// 2 blocks/CU, 2 waves/SIMD, phase-drifted free-running tap loop.
// ---------------------------------------------------------------------------
#define PREF_AF(dst, tap) {                                                   \
    const unsigned short* wp_ = wl + (size_t)(tap) * TAPSTRIDE;               \
    _Pragma("unroll")                                                         \
    for (int m = 0; m < 4; ++m)                                               \
        dst[m] = *(const short8*)(wp_ + (size_t)m * 16 * IC_);                \
}

#define PREF_BF(dst) {                                                        \
    int base_ = prow + (pkx + l15) * 64 +                                     \
                ((l4 ^ (((pkx + l15) & 7) >> 1)) << 4);                       \
    _Pragma("unroll")                                                         \
    for (int n = 0; n < 8; ++n)                                               \
        dst[n] = *(const short8*)(xsb + base_ + n * 1024);                    \
    if (++pkx == 5) { pkx = 0; prow += XROWB; }                               \
}

#define COMP(afx, bfx) {                                                      \
    __builtin_amdgcn_s_setprio(1);                                            \
    _Pragma("unroll")                                                         \
    for (int m = 0; m < 4; ++m)                                               \
        _Pragma("unroll")                                                     \
        for (int n = 0; n < 8; ++n)                                           \
            acc[m][n] = __builtin_amdgcn_mfma_f32_16x16x32_bf16(              \
                afx[m], bfx[n], acc[m][n], 0, 0, 0);                          \
    __builtin_amdgcn_s_setprio(0);                                            \
}

__global__ __launch_bounds__(256, 2) void conv_mfma_kernel(
    const unsigned short* __restrict__ xt,
    const unsigned short* __restrict__ wt,
    float* __restrict__ out) {
    // 8 rows x 132 w x 32 ic bf16 = 67584 B (chunk-swizzled via source)
    __shared__ __align__(16) unsigned short xs[8 * XTH * IC_];

    int tid  = threadIdx.x;
    int lane = tid & 63;
    int wv   = tid >> 6;          // 0..3 = wave's h row within slab
    int l15  = lane & 15;
    int l4   = lane >> 4;         // k-chunk (ic8 group)

    // ---- T1: bijective XCD-aware remap (nwg = 2048 = 8 * 256) ----
    int raw = blockIdx.x;
    int bid = (raw & 7) * 256 + (raw >> 3);
    int hp   = bid & 31;          // fastest: halo-sharing neighbors adjacent
    int b    = (bid >> 5) & 15;
    int pair = bid >> 9;          // 0..3; one pair per XCD (2 XCDs/pair)
    int h0 = hp * 4;

    // ---- stage x slab rows h0..h0+7 (linear dest, swizzled source) ----
    {
        const unsigned short* xb = xt + (((size_t)b * XTH + h0) * XTH) * IC_;
        #pragma unroll
        for (int i = 0; i < 17; ++i) {
            int sl = i * 256 + tid;     // 16B slots, 4224 total
            if (sl < 4224) {
                int row = sl / 528;
                int rem = sl - row * 528;
                int w   = rem >> 2;
                int p   = rem & 3;
                int c   = p ^ ((w >> 1) & 3);
                gload16(&xs[sl * 8], xb + row * (XTH * IC_) + w * 32 + c * 8);
            }
        }
    }

    // per-lane A base for cg = pair*2: co = pair*128 + m*16 + l15, ic-chunk l4
    const unsigned short* wl = wt + (size_t)(pair * 128 + l15) * IC_ + l4 * 8;
    const char* xsb = (const char*)xs;

    short8 afA[4], afB[4];
    PREF_AF(afA, 0);              // cg0 tap 0, overlaps x staging

    f32x4 acc[4][8];

    __syncthreads();              // xs ready (drains vmcnt)

    #pragma unroll 1
    for (int cgi = 0; cgi < 2; ++cgi) {
        #pragma unroll
        for (int m = 0; m < 4; ++m)
            #pragma unroll
            for (int n = 0; n < 8; ++n) acc[m][n] = (f32x4)(0.0f);

        int pkx  = 0;
        int prow = wv * XROWB;

        short8 bfA[8], bfB[8];
        PREF_BF(bfA);             // tap 0

        #pragma unroll 1
        for (int pi = 0; pi < 12; ++pi) {
            int t0 = pi * 2;
            PREF_AF(afB, t0 + 1);
            PREF_BF(bfB);
            COMP(afA, bfA);       // tap t0
            PREF_AF(afA, t0 + 2);
            PREF_BF(bfA);
            COMP(afB, bfB);       // tap t0+1
        }
        COMP(afA, bfA);           // tap 24

        // ---- prefetch next cg's tap-0 A BEFORE the stores ----
        // (issued ahead of stores; in-order retire means its first use
        //  does not force the store drain — stores drain under cg1 compute)
        const unsigned short* wlN = wl + (size_t)64 * IC_;
        if (cgi == 0) {
            #pragma unroll
            for (int m = 0; m < 4; ++m)
                afA[m] = *(const short8*)(wlN + (size_t)m * 16 * IC_);
        }

        // ---- epilogue: leaky relu + non-temporal store (current cg) ----
        int cobase = pair * 128 + cgi * 64;
        int h = h0 + wv;
        float* ob = out + ((size_t)b * COTOT_ + cobase) * HW2 + (size_t)h * HW_;
        #pragma unroll
        for (int m = 0; m < 4; ++m) {
            #pragma unroll
            for (int n = 0; n < 8; ++n) {
                #pragma unroll
                for (int r = 0; r < 4; ++r) {
                    int co = m * 16 + l4 * 4 + r;
                    int w  = n * 16 + l15;
                    float v = acc[m][n][r];
                    v = fmaxf(v, 0.01f * v);
                    __builtin_nontemporal_store(v, &ob[(size_t)co * HW2 + w]);
                }
            }
        }
        wl = wlN;                 // advance to next cg
    }
}

extern "C" void kernel_launch(void* const* d_in, const int* in_sizes, int n_in,
                              void* d_out, int out_size, void* d_ws, size_t ws_size,
                              hipStream_t stream) {
    const float* x       = (const float*)d_in[0];
    const float* kernel  = (const float*)d_in[1];
    const float* relaxed = (const float*)d_in[2];
    float* out = (float*)d_out;

    unsigned short* xt = (unsigned short*)d_ws;   // 16*132*132*32*2 = 17,842,176 B
    unsigned short* wt = (unsigned short*)((char*)d_ws + (size_t)B_ * XTH * XTH * IC_ * 2);

    const int xtot = B_ * XTH * XTH;
    xform_kernel<<<(xtot + 255) / 256, 256, 0, stream>>>(x, xt);

    const int wtot = 25 * COTOT_ * IC_;
    build_w_kernel<<<(wtot + 255) / 256, 256, 0, stream>>>(kernel, relaxed, wt);

    conv_mfma_kernel<<<2048, 256, 0, stream>>>(xt, wt, out);
}

// Round 21
// 369.271 us; speedup vs baseline: 1.2055x; 1.2055x over previous
//
#include <hip/hip_runtime.h>
#include <hip/hip_bf16.h>
#include <math.h>

// Problem constants
#define B_   16
#define IC_  32
#define HW_  128
#define NF_  8
#define OC_  64
#define K_   5
#define GRP_ 8
#define COTOT_ (OC_ * GRP_)   // 512
#define XTH  132              // padded spatial (128 + 2*2)
#define TAPSTRIDE (COTOT_ * IC_)   // elements per tap in wt
#define XROWB (XTH * IC_ * 2)      // 8448 bytes per xs row
#define HW2  (HW_ * HW_)

typedef short  short8  __attribute__((ext_vector_type(8)));
typedef unsigned short ushort8 __attribute__((ext_vector_type(8)));
typedef float  f32x4   __attribute__((ext_vector_type(4)));

static __device__ inline unsigned short f2bf(float f) {
    unsigned u = __builtin_bit_cast(unsigned, f);
    unsigned r = (u + 0x7FFFu + ((u >> 16) & 1u)) >> 16;
    return (unsigned short)r;
}

// async global -> LDS, 16 bytes per lane (dest = uniform base + lane*16)
__device__ __forceinline__ void gload16(void* lds, const void* g) {
    __builtin_amdgcn_global_load_lds(
        (const __attribute__((address_space(1))) unsigned int*)g,
        (__attribute__((address_space(3))) unsigned int*)lds, 16, 0, 0);
}

// ---------------------------------------------------------------------------
// Kernel 1: x NCHW fp32 -> padded NHWC bf16   xt[b][hp][wp][ic]
// ---------------------------------------------------------------------------
__global__ __launch_bounds__(256) void xform_kernel(
    const float* __restrict__ x, unsigned short* __restrict__ xt) {
    int idx = blockIdx.x * blockDim.x + threadIdx.x;
    const int TOT = B_ * XTH * XTH;
    if (idx >= TOT) return;
    int wp = idx % XTH;
    int t  = idx / XTH;
    int hp = t % XTH;
    int b  = t / XTH;

    unsigned short vals[IC_];
    bool interior = (hp >= 2) && (hp < 2 + HW_) && (wp >= 2) && (wp < 2 + HW_);
    if (interior) {
        const float* xb = x + ((size_t)b * IC_) * HW2 + (hp - 2) * HW_ + (wp - 2);
        #pragma unroll
        for (int ic = 0; ic < IC_; ++ic)
            vals[ic] = f2bf(xb[(size_t)ic * HW2]);
    } else {
        #pragma unroll
        for (int ic = 0; ic < IC_; ++ic) vals[ic] = 0;
    }
    ushort8* dst = (ushort8*)(xt + (size_t)idx * IC_);
    #pragma unroll
    for (int c = 0; c < 4; ++c) {
        ushort8 v;
        #pragma unroll
        for (int j = 0; j < 8; ++j) v[j] = vals[c * 8 + j];
        dst[c] = v;
    }
}

// ---------------------------------------------------------------------------
// Kernel 2: rotated+mixed weights -> bf16, layout wt[tap25][co512][ic32]
// ---------------------------------------------------------------------------
__global__ __launch_bounds__(256) void build_w_kernel(
    const float* __restrict__ kern,
    const float* __restrict__ relaxed,
    unsigned short* __restrict__ wt) {
    int idx = blockIdx.x * blockDim.x + threadIdx.x;
    const int TOT = 25 * COTOT_ * IC_;
    if (idx >= TOT) return;
    int ic = idx & (IC_ - 1);
    int t  = idx >> 5;
    int co = t & (COTOT_ - 1);
    int e  = t >> 9;            // ky*5+kx
    int a  = co & (GRP_ - 1);
    int o  = co >> 3;
    int i  = e / K_;            // ky
    int j  = e - i * K_;        // kx

    float theta = -6.283185307179586f / (float)GRP_ * (float)a;
    float cth = cosf(theta), sth = sinf(theta);
    float bx = (2.0f * (float)j + 1.0f) / (float)K_ - 1.0f;
    float by = (2.0f * (float)i + 1.0f) / (float)K_ - 1.0f;
    float gx = cth * bx - sth * by;
    float gy = sth * bx + cth * by;
    float ix = ((gx + 1.0f) * (float)K_ - 1.0f) * 0.5f;
    float iy = ((gy + 1.0f) * (float)K_ - 1.0f) * 0.5f;
    float x0 = floorf(ix), y0 = floorf(iy);
    float wx1 = ix - x0, wy1 = iy - y0;
    float wx0 = 1.0f - wx1, wy0 = 1.0f - wy1;

    float xs2[2]  = {x0, x0 + 1.0f};
    float ys2[2]  = {y0, y0 + 1.0f};
    float wxs[2] = {wx0, wx1};
    float wys[2] = {wy0, wy1};

    float tw[4];
    int   tyc[4], txc[4];
    #pragma unroll
    for (int dy = 0; dy < 2; ++dy) {
        #pragma unroll
        for (int dx = 0; dx < 2; ++dx) {
            float xx = xs2[dx], yy = ys2[dy];
            bool valid = (xx >= 0.0f) && (xx < (float)K_) &&
                         (yy >= 0.0f) && (yy < (float)K_);
            int tp = dy * 2 + dx;
            tw[tp]  = wys[dy] * wxs[dx] * (valid ? 1.0f : 0.0f);
            txc[tp] = (int)fminf(fmaxf(xx, 0.0f), (float)(K_ - 1));
            tyc[tp] = (int)fminf(fmaxf(yy, 0.0f), (float)(K_ - 1));
        }
    }

    float acc = 0.0f;
    #pragma unroll
    for (int n = 0; n < NF_; ++n) {
        const float* kb = kern + ((size_t)((n * OC_ + o) * IC_ + ic)) * (K_ * K_);
        float v = 0.0f;
        #pragma unroll
        for (int tp = 0; tp < 4; ++tp)
            v += kb[tyc[tp] * K_ + txc[tp]] * tw[tp];
        acc += relaxed[n * GRP_ + a] * v;
    }
    wt[idx] = f2bf(acc);
}

// ---------------------------------------------------------------------------
// Kernel 3: MFMA implicit-GEMM conv + leaky relu
// (R18 structure + 2-cg persistent block, STRAIGHT-LINE two-pass — no
//  loop-carried arrays / pointer mutation, so regalloc matches R18's proven
//  allocation; R20's cg-loop version spilled: VGPR_Count=128, +1.2GB HBM)
// wave = 64 co x 128 w x 1 h (4x8 frags); block = 4 waves; LDS 67.5 KB
// 2 blocks/CU, 2 waves/SIMD, phase-drifted free-running tap loops.
// Pass 0 (cg=pair*2) -> prefetch cg1 tap-0 A -> stores0 -> Pass 1 -> stores1:
// cg0's store drain hides under cg1's full 25-tap compute; slab staged once.
// T1 bijective XCD remap (nwg=2048); NT stores (write-once output).
// ---------------------------------------------------------------------------
#define PREF_AF(dst, base, tap) {                                             \
    const unsigned short* wp_ = (base) + (size_t)(tap) * TAPSTRIDE;           \
    _Pragma("unroll")                                                         \
    for (int m = 0; m < 4; ++m)                                               \
        dst[m] = *(const short8*)(wp_ + (size_t)m * 16 * IC_);                \
}

#define PREF_BF(dst) {                                                        \
    int base_ = prow + (pkx + l15) * 64 +                                     \
                ((l4 ^ (((pkx + l15) & 7) >> 1)) << 4);                       \
    _Pragma("unroll")                                                         \
    for (int n = 0; n < 8; ++n)                                               \
        dst[n] = *(const short8*)(xsb + base_ + n * 1024);                    \
    if (++pkx == 5) { pkx = 0; prow += XROWB; }                               \
}

#define COMP(afx, bfx) {                                                      \
    __builtin_amdgcn_s_setprio(1);                                            \
    _Pragma("unroll")                                                         \
    for (int m = 0; m < 4; ++m)                                               \
        _Pragma("unroll")                                                     \
        for (int n = 0; n < 8; ++n)                                           \
            acc[m][n] = __builtin_amdgcn_mfma_f32_16x16x32_bf16(              \
                afx[m], bfx[n], acc[m][n], 0, 0, 0);                          \
    __builtin_amdgcn_s_setprio(0);                                            \
}

#define EPILOGUE(cob) {                                                       \
    int h = h0 + wv;                                                          \
    float* ob = out + ((size_t)b * COTOT_ + (cob)) * HW2 + (size_t)h * HW_;   \
    _Pragma("unroll")                                                         \
    for (int m = 0; m < 4; ++m)                                               \
        _Pragma("unroll")                                                     \
        for (int n = 0; n < 8; ++n)                                           \
            _Pragma("unroll")                                                 \
            for (int r = 0; r < 4; ++r) {                                     \
                int co = m * 16 + l4 * 4 + r;                                 \
                int w  = n * 16 + l15;                                        \
                float v = acc[m][n][r];                                       \
                v = fmaxf(v, 0.01f * v);                                      \
                __builtin_nontemporal_store(v, &ob[(size_t)co * HW2 + w]);    \
            }                                                                 \
}

__global__ __launch_bounds__(256, 2) void conv_mfma_kernel(
    const unsigned short* __restrict__ xt,
    const unsigned short* __restrict__ wt,
    float* __restrict__ out) {
    // 8 rows x 132 w x 32 ic bf16 = 67584 B (chunk-swizzled via source)
    __shared__ __align__(16) unsigned short xs[8 * XTH * IC_];

    int tid  = threadIdx.x;
    int lane = tid & 63;
    int wv   = tid >> 6;          // 0..3 = wave's h row within slab
    int l15  = lane & 15;
    int l4   = lane >> 4;         // k-chunk (ic8 group)

    // ---- T1: bijective XCD-aware remap (nwg = 2048 = 8 * 256) ----
    int raw = blockIdx.x;
    int bid = (raw & 7) * 256 + (raw >> 3);
    int hp   = bid & 31;          // fastest: halo-sharing neighbors adjacent
    int b    = (bid >> 5) & 15;
    int pair = bid >> 9;          // 0..3
    int h0 = hp * 4;

    // ---- stage x slab rows h0..h0+7 (linear dest, swizzled source) ----
    {
        const unsigned short* xb = xt + (((size_t)b * XTH + h0) * XTH) * IC_;
        #pragma unroll
        for (int i = 0; i < 17; ++i) {
            int sl = i * 256 + tid;     // 16B slots, 4224 total
            if (sl < 4224) {
                int row = sl / 528;
                int rem = sl - row * 528;
                int w   = rem >> 2;
                int p   = rem & 3;
                int c   = p ^ ((w >> 1) & 3);
                gload16(&xs[sl * 8], xb + row * (XTH * IC_) + w * 32 + c * 8);
            }
        }
    }

    const unsigned short* wl0 = wt + (size_t)(pair * 128 + l15) * IC_ + l4 * 8;
    const unsigned short* wl1 = wl0 + (size_t)64 * IC_;
    const char* xsb = (const char*)xs;

    short8 afA[4], afB[4];
    PREF_AF(afA, wl0, 0);         // cg0 tap 0, overlaps x staging

    f32x4 acc[4][8];
    #pragma unroll
    for (int m = 0; m < 4; ++m)
        #pragma unroll
        for (int n = 0; n < 8; ++n) acc[m][n] = (f32x4)(0.0f);

    __syncthreads();              // xs ready (drains vmcnt)

    short8 bfA[8], bfB[8];

    // ================= pass 0: cg = pair*2 =================
    {
        int pkx  = 0;
        int prow = wv * XROWB;
        PREF_BF(bfA);             // tap 0

        #pragma unroll 1
        for (int pi = 0; pi < 12; ++pi) {
            int t0 = pi * 2;
            PREF_AF(afB, wl0, t0 + 1);
            PREF_BF(bfB);
            COMP(afA, bfA);       // tap t0
            PREF_AF(afA, wl0, t0 + 2);
            PREF_BF(bfA);
            COMP(afB, bfB);       // tap t0+1
        }
        COMP(afA, bfA);           // tap 24
    }

    // prefetch cg1's tap-0 A BEFORE the stores (drain hides under pass 1)
    PREF_AF(afA, wl1, 0);

    EPILOGUE(pair * 128);

    // ================= pass 1: cg = pair*2 + 1 =================
    #pragma unroll
    for (int m = 0; m < 4; ++m)
        #pragma unroll
        for (int n = 0; n < 8; ++n) acc[m][n] = (f32x4)(0.0f);

    {
        int pkx  = 0;
        int prow = wv * XROWB;
        PREF_BF(bfA);             // tap 0

        #pragma unroll 1
        for (int pi = 0; pi < 12; ++pi) {
            int t0 = pi * 2;
            PREF_AF(afB, wl1, t0 + 1);
            PREF_BF(bfB);
            COMP(afA, bfA);       // tap t0
            PREF_AF(afA, wl1, t0 + 2);
            PREF_BF(bfA);
            COMP(afB, bfB);       // tap t0+1
        }
        COMP(afA, bfA);           // tap 24
    }

    EPILOGUE(pair * 128 + 64);
}

extern "C" void kernel_launch(void* const* d_in, const int* in_sizes, int n_in,
                              void* d_out, int out_size, void* d_ws, size_t ws_size,
                              hipStream_t stream) {
    const float* x       = (const float*)d_in[0];
    const float* kernel  = (const float*)d_in[1];
    const float* relaxed = (const float*)d_in[2];
    float* out = (float*)d_out;

    unsigned short* xt = (unsigned short*)d_ws;   // 16*132*132*32*2 = 17,842,176 B
    unsigned short* wt = (unsigned short*)((char*)d_ws + (size_t)B_ * XTH * XTH * IC_ * 2);

    const int xtot = B_ * XTH * XTH;
    xform_kernel<<<(xtot + 255) / 256, 256, 0, stream>>>(x, xt);

    const int wtot = 25 * COTOT_ * IC_;
    build_w_kernel<<<(wtot + 255) / 256, 256, 0, stream>>>(kernel, relaxed, wt);

    conv_mfma_kernel<<<2048, 256, 0, stream>>>(xt, wt, out);
}

// Round 22
// 221.232 us; speedup vs baseline: 2.0121x; 1.6692x over previous
//
#include <hip/hip_runtime.h>
#include <hip/hip_bf16.h>
#include <math.h>

// Problem constants
#define B_   16
#define IC_  32
#define HW_  128
#define NF_  8
#define OC_  64
#define K_   5
#define GRP_ 8
#define COTOT_ (OC_ * GRP_)   // 512
#define XTH  132              // padded spatial (128 + 2*2)
#define TAPSTRIDE (COTOT_ * IC_)   // elements per tap in wt
#define XROWB (XTH * IC_ * 2)      // 8448 bytes per xs row
#define HW2  (HW_ * HW_)

typedef short  short8  __attribute__((ext_vector_type(8)));
typedef unsigned short ushort8 __attribute__((ext_vector_type(8)));
typedef float  f32x4   __attribute__((ext_vector_type(4)));

static __device__ inline unsigned short f2bf(float f) {
    unsigned u = __builtin_bit_cast(unsigned, f);
    unsigned r = (u + 0x7FFFu + ((u >> 16) & 1u)) >> 16;
    return (unsigned short)r;
}

// async global -> LDS, 16 bytes per lane (dest = uniform base + lane*16)
__device__ __forceinline__ void gload16(void* lds, const void* g) {
    __builtin_amdgcn_global_load_lds(
        (const __attribute__((address_space(1))) unsigned int*)g,
        (__attribute__((address_space(3))) unsigned int*)lds, 16, 0, 0);
}

// ---------------------------------------------------------------------------
// Kernel 1: x NCHW fp32 -> padded NHWC bf16   xt[b][hp][wp][ic]
// ---------------------------------------------------------------------------
__global__ __launch_bounds__(256) void xform_kernel(
    const float* __restrict__ x, unsigned short* __restrict__ xt) {
    int idx = blockIdx.x * blockDim.x + threadIdx.x;
    const int TOT = B_ * XTH * XTH;
    if (idx >= TOT) return;
    int wp = idx % XTH;
    int t  = idx / XTH;
    int hp = t % XTH;
    int b  = t / XTH;

    unsigned short vals[IC_];
    bool interior = (hp >= 2) && (hp < 2 + HW_) && (wp >= 2) && (wp < 2 + HW_);
    if (interior) {
        const float* xb = x + ((size_t)b * IC_) * HW2 + (hp - 2) * HW_ + (wp - 2);
        #pragma unroll
        for (int ic = 0; ic < IC_; ++ic)
            vals[ic] = f2bf(xb[(size_t)ic * HW2]);
    } else {
        #pragma unroll
        for (int ic = 0; ic < IC_; ++ic) vals[ic] = 0;
    }
    ushort8* dst = (ushort8*)(xt + (size_t)idx * IC_);
    #pragma unroll
    for (int c = 0; c < 4; ++c) {
        ushort8 v;
        #pragma unroll
        for (int j = 0; j < 8; ++j) v[j] = vals[c * 8 + j];
        dst[c] = v;
    }
}

// ---------------------------------------------------------------------------
// Kernel 2: rotated+mixed weights -> bf16, layout wt[tap25][co512][ic32]
// ---------------------------------------------------------------------------
__global__ __launch_bounds__(256) void build_w_kernel(
    const float* __restrict__ kern,
    const float* __restrict__ relaxed,
    unsigned short* __restrict__ wt) {
    int idx = blockIdx.x * blockDim.x + threadIdx.x;
    const int TOT = 25 * COTOT_ * IC_;
    if (idx >= TOT) return;
    int ic = idx & (IC_ - 1);
    int t  = idx >> 5;
    int co = t & (COTOT_ - 1);
    int e  = t >> 9;            // ky*5+kx
    int a  = co & (GRP_ - 1);
    int o  = co >> 3;
    int i  = e / K_;            // ky
    int j  = e - i * K_;        // kx

    float theta = -6.283185307179586f / (float)GRP_ * (float)a;
    float cth = cosf(theta), sth = sinf(theta);
    float bx = (2.0f * (float)j + 1.0f) / (float)K_ - 1.0f;
    float by = (2.0f * (float)i + 1.0f) / (float)K_ - 1.0f;
    float gx = cth * bx - sth * by;
    float gy = sth * bx + cth * by;
    float ix = ((gx + 1.0f) * (float)K_ - 1.0f) * 0.5f;
    float iy = ((gy + 1.0f) * (float)K_ - 1.0f) * 0.5f;
    float x0 = floorf(ix), y0 = floorf(iy);
    float wx1 = ix - x0, wy1 = iy - y0;
    float wx0 = 1.0f - wx1, wy0 = 1.0f - wy1;

    float xs2[2]  = {x0, x0 + 1.0f};
    float ys2[2]  = {y0, y0 + 1.0f};
    float wxs[2] = {wx0, wx1};
    float wys[2] = {wy0, wy1};

    float tw[4];
    int   tyc[4], txc[4];
    #pragma unroll
    for (int dy = 0; dy < 2; ++dy) {
        #pragma unroll
        for (int dx = 0; dx < 2; ++dx) {
            float xx = xs2[dx], yy = ys2[dy];
            bool valid = (xx >= 0.0f) && (xx < (float)K_) &&
                         (yy >= 0.0f) && (yy < (float)K_);
            int tp = dy * 2 + dx;
            tw[tp]  = wys[dy] * wxs[dx] * (valid ? 1.0f : 0.0f);
            txc[tp] = (int)fminf(fmaxf(xx, 0.0f), (float)(K_ - 1));
            tyc[tp] = (int)fminf(fmaxf(yy, 0.0f), (float)(K_ - 1));
        }
    }

    float acc = 0.0f;
    #pragma unroll
    for (int n = 0; n < NF_; ++n) {
        const float* kb = kern + ((size_t)((n * OC_ + o) * IC_ + ic)) * (K_ * K_);
        float v = 0.0f;
        #pragma unroll
        for (int tp = 0; tp < 4; ++tp)
            v += kb[tyc[tp] * K_ + txc[tp]] * tw[tp];
        acc += relaxed[n * GRP_ + a] * v;
    }
    wt[idx] = f2bf(acc);
}

// ---------------------------------------------------------------------------
// Kernel 3: MFMA implicit-GEMM conv + leaky relu  (R18 — measured best 222 µs)
// wave  = 64 co x 128 w x 1 h (4x8 frags 16x16), acc 128 + dbufs ~= 239 VGPR
// block = 4 waves = 64 co x 4 h x 128 w; LDS 67.5 KB
// -> 2 blocks/CU, 2 waves/SIMD, PHASE-DRIFTED free-running tap loop.
// T1 grid swizzle (nwg=4096 % 8 == 0, bijective): XCD k gets exactly cg=k
// -> wt slice (200 KB) L2-resident per XCD; contiguous hp runs share halo
//    rows in L2 instead of re-fetching via L3.  (-19 µs measured, R18)
// A: global->VGPR reg-dbuf. B: swizzled LDS slab, reg-dbuf reads.
// ---------------------------------------------------------------------------
#define PREF_AF(dst, tap) {                                                   \
    const unsigned short* wp_ = wl + (size_t)(tap) * TAPSTRIDE;               \
    _Pragma("unroll")                                                         \
    for (int m = 0; m < 4; ++m)                                               \
        dst[m] = *(const short8*)(wp_ + (size_t)m * 16 * IC_);                \
}

#define PREF_BF(dst) {                                                        \
    int base_ = prow + (pkx + l15) * 64 +                                     \
                ((l4 ^ (((pkx + l15) & 7) >> 1)) << 4);                       \
    _Pragma("unroll")                                                         \
    for (int n = 0; n < 8; ++n)                                               \
        dst[n] = *(const short8*)(xsb + base_ + n * 1024);                    \
    if (++pkx == 5) { pkx = 0; prow += XROWB; }                               \
}

#define COMP(afx, bfx) {                                                      \
    __builtin_amdgcn_s_setprio(1);                                            \
    _Pragma("unroll")                                                         \
    for (int m = 0; m < 4; ++m)                                               \
        _Pragma("unroll")                                                     \
        for (int n = 0; n < 8; ++n)                                           \
            acc[m][n] = __builtin_amdgcn_mfma_f32_16x16x32_bf16(              \
                afx[m], bfx[n], acc[m][n], 0, 0, 0);                          \
    __builtin_amdgcn_s_setprio(0);                                            \
}

__global__ __launch_bounds__(256, 2) void conv_mfma_kernel(
    const unsigned short* __restrict__ xt,
    const unsigned short* __restrict__ wt,
    float* __restrict__ out) {
    // 8 rows x 132 w x 32 ic bf16 = 67584 B (chunk-swizzled via source)
    __shared__ __align__(16) unsigned short xs[8 * XTH * IC_];

    int tid  = threadIdx.x;
    int lane = tid & 63;
    int wv   = tid >> 6;          // 0..3 = wave's h row within slab
    int l15  = lane & 15;
    int l4   = lane >> 4;         // k-chunk (ic8 group)

    // ---- T1: bijective XCD-aware remap (nwg = 4096 = 8 * 512) ----
    int raw = blockIdx.x;
    int bid = (raw & 7) * 512 + (raw >> 3);
    int hp  = bid & 31;           // fastest: halo-sharing neighbors adjacent
    int b   = (bid >> 5) & 15;
    int cg  = bid >> 9;           // one cg per XCD
    int cobase = cg * 64;
    int h0 = hp * 4;

    // ---- stage x slab rows h0..h0+7 (linear dest, swizzled source) ----
    {
        const unsigned short* xb = xt + (((size_t)b * XTH + h0) * XTH) * IC_;
        #pragma unroll
        for (int i = 0; i < 17; ++i) {
            int sl = i * 256 + tid;     // 16B slots, 4224 total
            if (sl < 4224) {
                int row = sl / 528;
                int rem = sl - row * 528;
                int w   = rem >> 2;
                int p   = rem & 3;
                int c   = p ^ ((w >> 1) & 3);
                gload16(&xs[sl * 8], xb + row * (XTH * IC_) + w * 32 + c * 8);
            }
        }
    }

    // per-lane A base: co = cobase + m*16 + l15, ic-chunk l4
    const unsigned short* wl = wt + (size_t)(cobase + l15) * IC_ + l4 * 8;
    const char* xsb = (const char*)xs;

    short8 afA[4], afB[4];
    PREF_AF(afA, 0);              // overlaps x staging

    f32x4 acc[4][8];
    #pragma unroll
    for (int m = 0; m < 4; ++m)
        #pragma unroll
        for (int n = 0; n < 8; ++n) acc[m][n] = (f32x4)(0.0f);

    __syncthreads();              // xs ready (drains vmcnt)

    int pkx  = 0;
    int prow = wv * XROWB;

    short8 bfA[8], bfB[8];
    PREF_BF(bfA);                 // tap 0

    #pragma unroll 1
    for (int pi = 0; pi < 12; ++pi) {
        int t0 = pi * 2;
        PREF_AF(afB, t0 + 1);
        PREF_BF(bfB);
        COMP(afA, bfA);           // tap t0
        PREF_AF(afA, t0 + 2);
        PREF_BF(bfA);
        COMP(afB, bfB);           // tap t0+1
    }
    COMP(afA, bfA);               // tap 24

    // ---- epilogue: leaky relu + store ----
    int h = h0 + wv;
    float* ob = out + ((size_t)b * COTOT_ + cobase) * HW2 + (size_t)h * HW_;
    #pragma unroll
    for (int m = 0; m < 4; ++m) {
        #pragma unroll
        for (int n = 0; n < 8; ++n) {
            #pragma unroll
            for (int r = 0; r < 4; ++r) {
                int co = m * 16 + l4 * 4 + r;
                int w  = n * 16 + l15;
                float v = acc[m][n][r];
                v = fmaxf(v, 0.01f * v);
                ob[(size_t)co * HW2 + w] = v;
            }
        }
    }
}

extern "C" void kernel_launch(void* const* d_in, const int* in_sizes, int n_in,
                              void* d_out, int out_size, void* d_ws, size_t ws_size,
                              hipStream_t stream) {
    const float* x       = (const float*)d_in[0];
    const float* kernel  = (const float*)d_in[1];
    const float* relaxed = (const float*)d_in[2];
    float* out = (float*)d_out;

    unsigned short* xt = (unsigned short*)d_ws;   // 16*132*132*32*2 = 17,842,176 B
    unsigned short* wt = (unsigned short*)((char*)d_ws + (size_t)B_ * XTH * XTH * IC_ * 2);

    const int xtot = B_ * XTH * XTH;
    xform_kernel<<<(xtot + 255) / 256, 256, 0, stream>>>(x, xt);

    const int wtot = 25 * COTOT_ * IC_;
    build_w_kernel<<<(wtot + 255) / 256, 256, 0, stream>>>(kernel, relaxed, wt);

    conv_mfma_kernel<<<4096, 256, 0, stream>>>(xt, wt, out);
}